// Round 7
// baseline (417.377 us; speedup 1.0000x reference)
//
#include <hip/hip_runtime.h>
#include <math.h>

#define N_NODESC 100000
#define N_EDGESC 1600000
#define NBUCK 1563        // ceil(100000 / 64) -- 64 dst nodes per bucket
#define BSLACK 1280       // slots per bucket region (mean 1024 + 8 sigma)
#define SCHUNK 8192       // edges per scatter block
#define NSBLK 196         // ceil(1.6M / 8192)

// fast tanh: (e^2x - 1) / (e^2x + 1), clamped; ~1e-6 abs error, no libcall
__device__ __forceinline__ float fast_tanh(float x) {
    x = fminf(fmaxf(x, -15.f), 15.f);
    float e = __expf(2.f * x);
    return (e - 1.f) / (e + 1.f);
}

__global__ void binit_kernel(int* __restrict__ bcur) {
    int i = blockIdx.x * blockDim.x + threadIdx.x;
    if (i < NBUCK) bcur[i] = i * BSLACK;
}

// ---------------- fused fc1 (tanh) + filt GEMM + channel-0 attention score ----------------
// After writing h1, the block re-reads its own 32 KB of h1 (L2-hot, local XCD)
// and computes sum-over-nodes of tanh(h1 @ aw1 + b1) @ aw2 -> wsum[0].
__global__ __launch_bounds__(256) void gemm_kernel(
    const float* __restrict__ feat,
    const float* __restrict__ w1, const float* __restrict__ b1,
    const float* __restrict__ w2, const float* __restrict__ b2,
    const int* __restrict__ deg_out,
    float* __restrict__ h1, float* __restrict__ xs,
    const float* __restrict__ aw1, const float* __restrict__ ab1,
    const float* __restrict__ aw2, float* __restrict__ wsum) {
    __shared__ float sf[128 * 68];
    int tid = threadIdx.x;
    int base = blockIdx.x * 128;
    for (int k = 0; k < 8; k++) {
        int fi = tid + k * 256;
        int node = fi >> 4, f4 = fi & 15;
        float4 v = make_float4(0.f, 0.f, 0.f, 0.f);
        if (base + node < N_NODESC)
            v = ((const float4*)feat)[(size_t)(base + node) * 16 + f4];
        float* d = &sf[node * 68 + f4 * 4];
        d[0] = v.x; d[1] = v.y; d[2] = v.z; d[3] = v.w;
    }
    __syncthreads();

    int lane = tid & 63;
    int og = __builtin_amdgcn_readfirstlane(tid >> 6);
    const float* wp1 = w1 + og * 16 * 64;
    const float* wp2 = w2 + og * 16 * 64;

    float a1[2][16], a2[2][16];
#pragma unroll
    for (int o = 0; o < 16; o++) {
        float bb1 = b1[og * 16 + o], bb2 = b2[og * 16 + o];
        a1[0][o] = bb1; a1[1][o] = bb1;
        a2[0][o] = bb2; a2[1][o] = bb2;
    }

    for (int fq = 0; fq < 16; fq++) {
        float4 fv0 = *(const float4*)&sf[lane * 68 + fq * 4];
        float4 fv1 = *(const float4*)&sf[(lane + 64) * 68 + fq * 4];
#pragma unroll
        for (int o = 0; o < 16; o++) {
            float4 wv1 = *(const float4*)&wp1[o * 64 + fq * 4];
            float4 wv2 = *(const float4*)&wp2[o * 64 + fq * 4];
            a1[0][o] += fv0.x * wv1.x + fv0.y * wv1.y + fv0.z * wv1.z + fv0.w * wv1.w;
            a1[1][o] += fv1.x * wv1.x + fv1.y * wv1.y + fv1.z * wv1.z + fv1.w * wv1.w;
            a2[0][o] += fv0.x * wv2.x + fv0.y * wv2.y + fv0.z * wv2.z + fv0.w * wv2.w;
            a2[1][o] += fv1.x * wv2.x + fv1.y * wv2.y + fv1.z * wv2.z + fv1.w * wv2.w;
        }
    }

#pragma unroll
    for (int j = 0; j < 2; j++) {
        int g = base + lane + j * 64;
        if (g >= N_NODESC) continue;
        float is = rsqrtf(fmaxf((float)deg_out[g], 1.f));
#pragma unroll
        for (int oq = 0; oq < 4; oq++) {
            float4 t, u;
            t.x = fast_tanh(a1[j][oq * 4 + 0]); t.y = fast_tanh(a1[j][oq * 4 + 1]);
            t.z = fast_tanh(a1[j][oq * 4 + 2]); t.w = fast_tanh(a1[j][oq * 4 + 3]);
            u.x = a2[j][oq * 4 + 0] * is;   u.y = a2[j][oq * 4 + 1] * is;
            u.z = a2[j][oq * 4 + 2] * is;   u.w = a2[j][oq * 4 + 3] * is;
            ((float4*)h1)[(size_t)g * 16 + og * 4 + oq] = t;
            ((float4*)xs)[(size_t)g * 16 + og * 4 + oq] = u;
        }
    }

    // ---- channel-0 attention score: re-read own h1 rows (L2-hot) ----
    __syncthreads();   // drains vmcnt(0): h1 writes visible; L1 cold for h1 (first touch)
    int r = tid & 127;
    int kh = __builtin_amdgcn_readfirstlane(tid >> 7);    // wave-uniform k-half
    int g = min(base + r, N_NODESC - 1);
    const float4* rowp = (const float4*)(h1 + (size_t)g * 64);
    float acc[16];
#pragma unroll
    for (int k = 0; k < 16; k++) acc[k] = ab1[kh * 16 + k];
    for (int fq = 0; fq < 16; fq++) {
        float4 rv = rowp[fq];
#pragma unroll
        for (int k = 0; k < 16; k++) {
            int kk = kh * 16 + k;
            acc[k] += rv.x * aw1[(fq * 4 + 0) * 32 + kk]
                    + rv.y * aw1[(fq * 4 + 1) * 32 + kk]
                    + rv.z * aw1[(fq * 4 + 2) * 32 + kk]
                    + rv.w * aw1[(fq * 4 + 3) * 32 + kk];
        }
    }
    float s = 0.f;
#pragma unroll
    for (int k = 0; k < 16; k++) s += fast_tanh(acc[k]) * aw2[kh * 16 + k];
    if (base + r >= N_NODESC) s = 0.f;
#pragma unroll
    for (int off = 32; off; off >>= 1) s += __shfl_down(s, off, 64);
    if ((tid & 63) == 0) atomicAdd(&wsum[0], s);
}

// ---------------- per-block staged counting sort into fixed bucket regions ----------------
__global__ __launch_bounds__(1024) void scatter2_kernel(const int* __restrict__ src,
                                                        const int* __restrict__ dst,
                                                        int* __restrict__ bcur,
                                                        unsigned* __restrict__ bedges,
                                                        int* __restrict__ deg_out) {
    __shared__ int hist[NBUCK];
    int tid = threadIdx.x;
    int e_beg = blockIdx.x * SCHUNK;
    int e_end = min(e_beg + SCHUNK, N_EDGESC);
    for (int i = tid; i < NBUCK; i += 1024) hist[i] = 0;
    __syncthreads();
#pragma unroll 4
    for (int i = e_beg + tid; i < e_end; i += 1024)
        atomicAdd(&hist[dst[i] >> 6], 1);
    __syncthreads();
    for (int i = tid; i < NBUCK; i += 1024) {
        int c = hist[i];
        if (c > 0) hist[i] = atomicAdd(&bcur[i], c);
    }
    __syncthreads();
#pragma unroll 4
    for (int i = e_beg + tid; i < e_end; i += 1024) {
        int s = src[i], d = dst[i];
        int slot = atomicAdd(&hist[d >> 6], 1);
        bedges[slot] = (unsigned)s | ((unsigned)(d & 63) << 17);
        atomicAdd(&deg_out[s], 1);
    }
}

// ---------------- per-bucket aggregation + channel-1 attention score ----------------
__global__ __launch_bounds__(256) void agg4_kernel(const int* __restrict__ bcur,
                                                   const unsigned* __restrict__ bedges,
                                                   const float* __restrict__ xs,
                                                   float* __restrict__ h2,
                                                   const float* __restrict__ aw1,
                                                   const float* __restrict__ ab1,
                                                   const float* __restrict__ aw2,
                                                   float* __restrict__ wsum) {
    __shared__ unsigned eraw[BSLACK];
    __shared__ unsigned eled[BSLACK];
    __shared__ int loff[65];
    __shared__ int lcnt[64];
    __shared__ int lcur[64];
    int tid = threadIdx.x, lane = tid & 63, wid = tid >> 6;
    int b = blockIdx.x;
    int beg = b * BSLACK;
    int m = bcur[b] - beg;             // edges in this bucket

    if (tid < 64) lcnt[tid] = 0;
    __syncthreads();
    for (int i = tid; i < m; i += 256) {
        unsigned pk = bedges[beg + i];
        eraw[i] = pk;
        atomicAdd(&lcnt[pk >> 17], 1);
    }
    __syncthreads();
    if (wid == 0) {                    // 64-entry exclusive scan in wave 0
        int c = lcnt[lane];
        int v = c;
#pragma unroll
        for (int off = 1; off < 64; off <<= 1) {
            int t = __shfl_up(v, off, 64);
            if (lane >= off) v += t;
        }
        loff[lane] = v - c;
        lcur[lane] = v - c;
        if (lane == 63) loff[64] = v;  // == m
    }
    __syncthreads();
    for (int i = tid; i < m; i += 256) {
        unsigned pk = eraw[i];
        int pos = atomicAdd(&lcur[pk >> 17], 1);
        eled[pos] = pk & 0x1FFFFu;
    }
    __syncthreads();

    int nbase = b * 64;
#pragma unroll 1
    for (int t = 0; t < 16; t++) {
        int nl = wid * 16 + t;
        int s0 = loff[nl], s1 = loff[nl + 1];
        float acc = 0.f;
        for (int k = s0; k < s1; k += 16) {
            int cnt = s1 - k; if (cnt > 16) cnt = 16;   // wave-uniform
            unsigned sv = eled[min(k + (lane & 15), s1 - 1)];
            float v[16];
#pragma unroll
            for (int j = 0; j < 16; j++) {
                if (j < cnt) {
                    int sj = __shfl((int)sv, j, 64);
                    v[j] = xs[(size_t)sj * 64 + lane];
                }
            }
#pragma unroll
            for (int j = 0; j < 16; j++)
                if (j < cnt) acc += v[j];
        }
        int g = nbase + nl;
        if (g < N_NODESC) {
            float isq = rsqrtf(fmaxf((float)(s1 - s0), 1.f));
            h2[(size_t)g * 64 + lane] = acc * isq;
        }
    }

    // ---- channel-1 attention score: re-read own h2 rows (L2-hot) ----
    __syncthreads();   // drains vmcnt(0): h2 writes visible; L1 cold for h2 (first touch)
    int r = tid & 63;
    int kq = __builtin_amdgcn_readfirstlane(tid >> 6);    // wave-uniform k-quarter (8 k's)
    int g = min(nbase + r, N_NODESC - 1);
    const float4* rowp = (const float4*)(h2 + (size_t)g * 64);
    float acc2[8];
#pragma unroll
    for (int k = 0; k < 8; k++) acc2[k] = ab1[kq * 8 + k];
    for (int fq = 0; fq < 16; fq++) {
        float4 rv = rowp[fq];
#pragma unroll
        for (int k = 0; k < 8; k++) {
            int kk = kq * 8 + k;
            acc2[k] += rv.x * aw1[(fq * 4 + 0) * 32 + kk]
                     + rv.y * aw1[(fq * 4 + 1) * 32 + kk]
                     + rv.z * aw1[(fq * 4 + 2) * 32 + kk]
                     + rv.w * aw1[(fq * 4 + 3) * 32 + kk];
        }
    }
    float s = 0.f;
#pragma unroll
    for (int k = 0; k < 8; k++) s += fast_tanh(acc2[k]) * aw2[kq * 8 + k];
    if (nbase + r >= N_NODESC) s = 0.f;
#pragma unroll
    for (int off = 32; off; off >>= 1) s += __shfl_down(s, off, 64);
    if ((tid & 63) == 0) atomicAdd(&wsum[1], s);
}

__global__ void beta_kernel(const float* __restrict__ wsum, float* __restrict__ beta) {
    float w0 = wsum[0] / (float)N_NODESC, w1 = wsum[1] / (float)N_NODESC;
    float m = fmaxf(w0, w1);
    float e0 = expf(w0 - m), e1 = expf(w1 - m);
    float inv = 1.f / (e0 + e1);
    beta[0] = e0 * inv;
    beta[1] = e1 * inv;
}

// ---------------- fused combine + fc2 ----------------
__global__ __launch_bounds__(256) void out_kernel(const float* __restrict__ h1,
                                                  const float* __restrict__ h2,
                                                  const float* __restrict__ beta,
                                                  const float* __restrict__ w,
                                                  const float* __restrict__ b,
                                                  float* __restrict__ out) {
    __shared__ float sw[16 * 68];
    int tid = threadIdx.x;
    {
        int o = tid >> 4, f4 = tid & 15;
        float4 v = ((const float4*)w)[tid];
        float* d = &sw[o * 68 + f4 * 4];
        d[0] = v.x; d[1] = v.y; d[2] = v.z; d[3] = v.w;
    }
    __syncthreads();
    int o = tid & 15, ln = tid >> 4;
    int node = blockIdx.x * 16 + ln;
    if (node >= N_NODESC) return;
    float b0 = beta[0], b1v = beta[1];
    const float4* r1 = (const float4*)(h1 + (size_t)node * 64);
    const float4* r2 = (const float4*)(h2 + (size_t)node * 64);
    float acc = b[o];
    for (int fq = 0; fq < 16; fq++) {
        float4 x1 = r1[fq], x2 = r2[fq];
        float4 wv = *(const float4*)&sw[o * 68 + fq * 4];
        acc += (b0 * x1.x + b1v * x2.x) * wv.x + (b0 * x1.y + b1v * x2.y) * wv.y
             + (b0 * x1.z + b1v * x2.z) * wv.z + (b0 * x1.w + b1v * x2.w) * wv.w;
    }
    out[(size_t)node * 16 + o] = acc;
}

extern "C" void kernel_launch(void* const* d_in, const int* in_sizes, int n_in,
                              void* d_out, int out_size, void* d_ws, size_t ws_size,
                              hipStream_t stream) {
    (void)in_sizes; (void)n_in; (void)out_size; (void)ws_size;
    const float* feat = (const float*)d_in[0];
    const int*   esrc = (const int*)d_in[1];
    const int*   edst = (const int*)d_in[2];
    const float* fc1w = (const float*)d_in[3];
    const float* fc1b = (const float*)d_in[4];
    const float* fltw = (const float*)d_in[5];
    const float* fltb = (const float*)d_in[6];
    const float* aw1  = (const float*)d_in[7];
    const float* ab1  = (const float*)d_in[8];
    const float* aw2  = (const float*)d_in[9];
    const float* fc2w = (const float*)d_in[10];
    const float* fc2b = (const float*)d_in[11];
    float* out = (float*)d_out;

    char* ws = (char*)d_ws;
    size_t off = 0;
    auto alloc = [&](size_t bytes) {
        char* p = ws + off;
        off += (bytes + 255) & ~(size_t)255;
        return p;
    };
    float*    h1      = (float*)alloc((size_t)N_NODESC * 64 * 4);
    float*    xs      = (float*)alloc((size_t)N_NODESC * 64 * 4);
    float*    h2      = (float*)alloc((size_t)N_NODESC * 64 * 4);
    int*      deg_out = (int*)alloc((size_t)N_NODESC * 4);
    int*      bcur    = (int*)alloc((size_t)NBUCK * 4);
    unsigned* bedges  = (unsigned*)alloc((size_t)NBUCK * BSLACK * 4);  // 8 MB
    float*    wsum    = (float*)alloc(16 * 4);
    float*    beta    = (float*)alloc(16 * 4);

    hipMemsetAsync(deg_out, 0, (size_t)N_NODESC * 4, stream);
    hipMemsetAsync(wsum, 0, 2 * 4, stream);

    binit_kernel<<<(NBUCK + 255) / 256, 256, 0, stream>>>(bcur);
    scatter2_kernel<<<NSBLK, 1024, 0, stream>>>(esrc, edst, bcur, bedges, deg_out);
    gemm_kernel<<<(N_NODESC + 127) / 128, 256, 0, stream>>>(
        feat, fc1w, fc1b, fltw, fltb, deg_out, h1, xs, aw1, ab1, aw2, wsum);
    agg4_kernel<<<NBUCK, 256, 0, stream>>>(bcur, bedges, xs, h2, aw1, ab1, aw2, wsum);
    beta_kernel<<<1, 1, 0, stream>>>(wsum, beta);
    out_kernel<<<(N_NODESC + 15) / 16, 256, 0, stream>>>(h1, h2, beta, fc2w, fc2b, out);
}

// Round 8
// 407.807 us; speedup vs baseline: 1.0235x; 1.0235x over previous
//
#include <hip/hip_runtime.h>
#include <math.h>

#define N_NODESC 100000
#define N_EDGESC 1600000
#define NBUCK 1563        // ceil(100000 / 64) -- 64 dst nodes per bucket
#define BSLACK 1280       // slots per bucket region (mean 1024 + 8 sigma)
#define SCHUNK 8192       // edges per scatter block
#define NSBLK 196         // ceil(1.6M / 8192)

// fast tanh: (e^2x - 1) / (e^2x + 1), clamped; ~1e-6 abs error, no libcall
__device__ __forceinline__ float fast_tanh(float x) {
    x = fminf(fmaxf(x, -15.f), 15.f);
    float e = __expf(2.f * x);
    return (e - 1.f) / (e + 1.f);
}

__global__ void binit_kernel(int* __restrict__ bcur) {
    int i = blockIdx.x * blockDim.x + threadIdx.x;
    if (i < NBUCK) bcur[i] = i * BSLACK;
}

// ---------------- fused fc1 (tanh) + filt GEMM + channel-0 attention score ----------------
// h1 tile is written into LDS (reusing sf) in the epilogue; the attention
// score is computed from LDS -- no cold/uncoalesced global re-read.
__global__ __launch_bounds__(256) void gemm_kernel(
    const float* __restrict__ feat,
    const float* __restrict__ w1, const float* __restrict__ b1,
    const float* __restrict__ w2, const float* __restrict__ b2,
    const int* __restrict__ deg_out,
    float* __restrict__ h1, float* __restrict__ xs,
    const float* __restrict__ aw1, const float* __restrict__ ab1,
    const float* __restrict__ aw2, float* __restrict__ wsum) {
    __shared__ float sf[128 * 68];    // phase 1: feat tile; phase 2: h1 tile
    int tid = threadIdx.x;
    int base = blockIdx.x * 128;
    for (int k = 0; k < 8; k++) {
        int fi = tid + k * 256;
        int node = fi >> 4, f4 = fi & 15;
        float4 v = make_float4(0.f, 0.f, 0.f, 0.f);
        if (base + node < N_NODESC)
            v = ((const float4*)feat)[(size_t)(base + node) * 16 + f4];
        float* d = &sf[node * 68 + f4 * 4];
        d[0] = v.x; d[1] = v.y; d[2] = v.z; d[3] = v.w;
    }
    __syncthreads();

    int lane = tid & 63;
    int og = __builtin_amdgcn_readfirstlane(tid >> 6);
    const float* wp1 = w1 + og * 16 * 64;
    const float* wp2 = w2 + og * 16 * 64;

    float a1[2][16], a2[2][16];
#pragma unroll
    for (int o = 0; o < 16; o++) {
        float bb1 = b1[og * 16 + o], bb2 = b2[og * 16 + o];
        a1[0][o] = bb1; a1[1][o] = bb1;
        a2[0][o] = bb2; a2[1][o] = bb2;
    }

    for (int fq = 0; fq < 16; fq++) {
        float4 fv0 = *(const float4*)&sf[lane * 68 + fq * 4];
        float4 fv1 = *(const float4*)&sf[(lane + 64) * 68 + fq * 4];
#pragma unroll
        for (int o = 0; o < 16; o++) {
            float4 wv1 = *(const float4*)&wp1[o * 64 + fq * 4];
            float4 wv2 = *(const float4*)&wp2[o * 64 + fq * 4];
            a1[0][o] += fv0.x * wv1.x + fv0.y * wv1.y + fv0.z * wv1.z + fv0.w * wv1.w;
            a1[1][o] += fv1.x * wv1.x + fv1.y * wv1.y + fv1.z * wv1.z + fv1.w * wv1.w;
            a2[0][o] += fv0.x * wv2.x + fv0.y * wv2.y + fv0.z * wv2.z + fv0.w * wv2.w;
            a2[1][o] += fv1.x * wv2.x + fv1.y * wv2.y + fv1.z * wv2.z + fv1.w * wv2.w;
        }
    }

    __syncthreads();   // all waves done reading feat tile; sf becomes h1 tile
#pragma unroll
    for (int j = 0; j < 2; j++) {
        int row = lane + j * 64;
        int g = base + row;
        bool ok = g < N_NODESC;
        float is = ok ? rsqrtf(fmaxf((float)deg_out[g], 1.f)) : 0.f;
#pragma unroll
        for (int oq = 0; oq < 4; oq++) {
            float4 t, u;
            t.x = fast_tanh(a1[j][oq * 4 + 0]); t.y = fast_tanh(a1[j][oq * 4 + 1]);
            t.z = fast_tanh(a1[j][oq * 4 + 2]); t.w = fast_tanh(a1[j][oq * 4 + 3]);
            u.x = a2[j][oq * 4 + 0] * is;   u.y = a2[j][oq * 4 + 1] * is;
            u.z = a2[j][oq * 4 + 2] * is;   u.w = a2[j][oq * 4 + 3] * is;
            *(float4*)&sf[row * 68 + (og * 4 + oq) * 4] = t;   // h1 tile into LDS
            if (ok) {
                ((float4*)h1)[(size_t)g * 16 + og * 4 + oq] = t;
                ((float4*)xs)[(size_t)g * 16 + og * 4 + oq] = u;
            }
        }
    }
    __syncthreads();

    // ---- channel-0 attention score from the LDS h1 tile ----
    int r = tid & 127;
    int kh = __builtin_amdgcn_readfirstlane(tid >> 7);    // wave-uniform k-half
    float acc[16];
#pragma unroll
    for (int k = 0; k < 16; k++) acc[k] = ab1[kh * 16 + k];
    for (int fq = 0; fq < 16; fq++) {
        float4 rv = *(const float4*)&sf[r * 68 + fq * 4];
#pragma unroll
        for (int k = 0; k < 16; k++) {
            int kk = kh * 16 + k;
            acc[k] += rv.x * aw1[(fq * 4 + 0) * 32 + kk]
                    + rv.y * aw1[(fq * 4 + 1) * 32 + kk]
                    + rv.z * aw1[(fq * 4 + 2) * 32 + kk]
                    + rv.w * aw1[(fq * 4 + 3) * 32 + kk];
        }
    }
    float s = 0.f;
#pragma unroll
    for (int k = 0; k < 16; k++) s += fast_tanh(acc[k]) * aw2[kh * 16 + k];
    if (base + r >= N_NODESC) s = 0.f;
#pragma unroll
    for (int off = 32; off; off >>= 1) s += __shfl_down(s, off, 64);
    if ((tid & 63) == 0) atomicAdd(&wsum[0], s);
}

// ---------------- per-block staged counting sort into fixed bucket regions ----------------
__global__ __launch_bounds__(1024) void scatter2_kernel(const int* __restrict__ src,
                                                        const int* __restrict__ dst,
                                                        int* __restrict__ bcur,
                                                        unsigned* __restrict__ bedges,
                                                        int* __restrict__ deg_out) {
    __shared__ int hist[NBUCK];
    int tid = threadIdx.x;
    int e_beg = blockIdx.x * SCHUNK;
    int e_end = min(e_beg + SCHUNK, N_EDGESC);
    for (int i = tid; i < NBUCK; i += 1024) hist[i] = 0;
    __syncthreads();
#pragma unroll 4
    for (int i = e_beg + tid; i < e_end; i += 1024)
        atomicAdd(&hist[dst[i] >> 6], 1);
    __syncthreads();
    for (int i = tid; i < NBUCK; i += 1024) {
        int c = hist[i];
        if (c > 0) hist[i] = atomicAdd(&bcur[i], c);
    }
    __syncthreads();
#pragma unroll 4
    for (int i = e_beg + tid; i < e_end; i += 1024) {
        int s = src[i], d = dst[i];
        int slot = atomicAdd(&hist[d >> 6], 1);
        bedges[slot] = (unsigned)s | ((unsigned)(d & 63) << 17);
        atomicAdd(&deg_out[s], 1);
    }
}

// ---------------- per-bucket aggregation + channel-1 attention score (from LDS) ----------------
__global__ __launch_bounds__(256) void agg4_kernel(const int* __restrict__ bcur,
                                                   const unsigned* __restrict__ bedges,
                                                   const float* __restrict__ xs,
                                                   float* __restrict__ h2,
                                                   const float* __restrict__ aw1,
                                                   const float* __restrict__ ab1,
                                                   const float* __restrict__ aw2,
                                                   float* __restrict__ wsum) {
    __shared__ unsigned eraw[BSLACK];
    __shared__ unsigned eled[BSLACK];
    __shared__ float sh2[64 * 68];     // h2 tile for the attention phase
    __shared__ int loff[65];
    __shared__ int lcnt[64];
    __shared__ int lcur[64];
    int tid = threadIdx.x, lane = tid & 63, wid = tid >> 6;
    int b = blockIdx.x;
    int beg = b * BSLACK;
    int m = bcur[b] - beg;             // edges in this bucket

    if (tid < 64) lcnt[tid] = 0;
    __syncthreads();
    for (int i = tid; i < m; i += 256) {
        unsigned pk = bedges[beg + i];
        eraw[i] = pk;
        atomicAdd(&lcnt[pk >> 17], 1);
    }
    __syncthreads();
    if (wid == 0) {                    // 64-entry exclusive scan in wave 0
        int c = lcnt[lane];
        int v = c;
#pragma unroll
        for (int off = 1; off < 64; off <<= 1) {
            int t = __shfl_up(v, off, 64);
            if (lane >= off) v += t;
        }
        loff[lane] = v - c;
        lcur[lane] = v - c;
        if (lane == 63) loff[64] = v;  // == m
    }
    __syncthreads();
    for (int i = tid; i < m; i += 256) {
        unsigned pk = eraw[i];
        int pos = atomicAdd(&lcur[pk >> 17], 1);
        eled[pos] = pk & 0x1FFFFu;
    }
    __syncthreads();

    int nbase = b * 64;
#pragma unroll 1
    for (int t = 0; t < 16; t++) {
        int nl = wid * 16 + t;
        int s0 = loff[nl], s1 = loff[nl + 1];
        float acc = 0.f;
        for (int k = s0; k < s1; k += 16) {
            int cnt = s1 - k; if (cnt > 16) cnt = 16;   // wave-uniform
            unsigned sv = eled[min(k + (lane & 15), s1 - 1)];
            float v[16];
            // loads are unconditional (indices clamped-valid) so all 16 stay
            // independent and in flight; the guard is applied at accumulate.
#pragma unroll
            for (int j = 0; j < 16; j++) {
                int sj = __shfl((int)sv, j, 64);
                v[j] = xs[(size_t)sj * 64 + lane];
            }
#pragma unroll
            for (int j = 0; j < 16; j++)
                acc += (j < cnt) ? v[j] : 0.f;
        }
        float isq = rsqrtf(fmaxf((float)(s1 - s0), 1.f));
        float hv = acc * isq;
        sh2[nl * 68 + lane] = hv;                 // lane=feature -> 2-way, free
        int g = nbase + nl;
        if (g < N_NODESC) h2[(size_t)g * 64 + lane] = hv;
    }
    __syncthreads();

    // ---- channel-1 attention score from the LDS h2 tile ----
    int r = tid & 63;
    int kq = __builtin_amdgcn_readfirstlane(tid >> 6);    // wave-uniform k-quarter
    float acc2[8];
#pragma unroll
    for (int k = 0; k < 8; k++) acc2[k] = ab1[kq * 8 + k];
    for (int fq = 0; fq < 16; fq++) {
        float4 rv = *(const float4*)&sh2[r * 68 + fq * 4];
#pragma unroll
        for (int k = 0; k < 8; k++) {
            int kk = kq * 8 + k;
            acc2[k] += rv.x * aw1[(fq * 4 + 0) * 32 + kk]
                     + rv.y * aw1[(fq * 4 + 1) * 32 + kk]
                     + rv.z * aw1[(fq * 4 + 2) * 32 + kk]
                     + rv.w * aw1[(fq * 4 + 3) * 32 + kk];
        }
    }
    float s = 0.f;
#pragma unroll
    for (int k = 0; k < 8; k++) s += fast_tanh(acc2[k]) * aw2[kq * 8 + k];
    if (nbase + r >= N_NODESC) s = 0.f;
#pragma unroll
    for (int off = 32; off; off >>= 1) s += __shfl_down(s, off, 64);
    if ((tid & 63) == 0) atomicAdd(&wsum[1], s);
}

__global__ void beta_kernel(const float* __restrict__ wsum, float* __restrict__ beta) {
    float w0 = wsum[0] / (float)N_NODESC, w1 = wsum[1] / (float)N_NODESC;
    float m = fmaxf(w0, w1);
    float e0 = expf(w0 - m), e1 = expf(w1 - m);
    float inv = 1.f / (e0 + e1);
    beta[0] = e0 * inv;
    beta[1] = e1 * inv;
}

// ---------------- fused combine + fc2 ----------------
__global__ __launch_bounds__(256) void out_kernel(const float* __restrict__ h1,
                                                  const float* __restrict__ h2,
                                                  const float* __restrict__ beta,
                                                  const float* __restrict__ w,
                                                  const float* __restrict__ b,
                                                  float* __restrict__ out) {
    __shared__ float sw[16 * 68];
    int tid = threadIdx.x;
    {
        int o = tid >> 4, f4 = tid & 15;
        float4 v = ((const float4*)w)[tid];
        float* d = &sw[o * 68 + f4 * 4];
        d[0] = v.x; d[1] = v.y; d[2] = v.z; d[3] = v.w;
    }
    __syncthreads();
    int o = tid & 15, ln = tid >> 4;
    int node = blockIdx.x * 16 + ln;
    if (node >= N_NODESC) return;
    float b0 = beta[0], b1v = beta[1];
    const float4* r1 = (const float4*)(h1 + (size_t)node * 64);
    const float4* r2 = (const float4*)(h2 + (size_t)node * 64);
    float acc = b[o];
    for (int fq = 0; fq < 16; fq++) {
        float4 x1 = r1[fq], x2 = r2[fq];
        float4 wv = *(const float4*)&sw[o * 68 + fq * 4];
        acc += (b0 * x1.x + b1v * x2.x) * wv.x + (b0 * x1.y + b1v * x2.y) * wv.y
             + (b0 * x1.z + b1v * x2.z) * wv.z + (b0 * x1.w + b1v * x2.w) * wv.w;
    }
    out[(size_t)node * 16 + o] = acc;
}

extern "C" void kernel_launch(void* const* d_in, const int* in_sizes, int n_in,
                              void* d_out, int out_size, void* d_ws, size_t ws_size,
                              hipStream_t stream) {
    (void)in_sizes; (void)n_in; (void)out_size; (void)ws_size;
    const float* feat = (const float*)d_in[0];
    const int*   esrc = (const int*)d_in[1];
    const int*   edst = (const int*)d_in[2];
    const float* fc1w = (const float*)d_in[3];
    const float* fc1b = (const float*)d_in[4];
    const float* fltw = (const float*)d_in[5];
    const float* fltb = (const float*)d_in[6];
    const float* aw1  = (const float*)d_in[7];
    const float* ab1  = (const float*)d_in[8];
    const float* aw2  = (const float*)d_in[9];
    const float* fc2w = (const float*)d_in[10];
    const float* fc2b = (const float*)d_in[11];
    float* out = (float*)d_out;

    char* ws = (char*)d_ws;
    size_t off = 0;
    auto alloc = [&](size_t bytes) {
        char* p = ws + off;
        off += (bytes + 255) & ~(size_t)255;
        return p;
    };
    float*    h1      = (float*)alloc((size_t)N_NODESC * 64 * 4);
    float*    xs      = (float*)alloc((size_t)N_NODESC * 64 * 4);
    float*    h2      = (float*)alloc((size_t)N_NODESC * 64 * 4);
    int*      deg_out = (int*)alloc((size_t)N_NODESC * 4);
    int*      bcur    = (int*)alloc((size_t)NBUCK * 4);
    unsigned* bedges  = (unsigned*)alloc((size_t)NBUCK * BSLACK * 4);  // 8 MB
    float*    wsum    = (float*)alloc(16 * 4);
    float*    beta    = (float*)alloc(16 * 4);

    hipMemsetAsync(deg_out, 0, (size_t)N_NODESC * 4, stream);
    hipMemsetAsync(wsum, 0, 2 * 4, stream);

    binit_kernel<<<(NBUCK + 255) / 256, 256, 0, stream>>>(bcur);
    scatter2_kernel<<<NSBLK, 1024, 0, stream>>>(esrc, edst, bcur, bedges, deg_out);
    gemm_kernel<<<(N_NODESC + 127) / 128, 256, 0, stream>>>(
        feat, fc1w, fc1b, fltw, fltb, deg_out, h1, xs, aw1, ab1, aw2, wsum);
    agg4_kernel<<<NBUCK, 256, 0, stream>>>(bcur, bedges, xs, h2, aw1, ab1, aw2, wsum);
    beta_kernel<<<1, 1, 0, stream>>>(wsum, beta);
    out_kernel<<<(N_NODESC + 15) / 16, 256, 0, stream>>>(h1, h2, beta, fc2w, fc2b, out);
}

// Round 9
// 386.986 us; speedup vs baseline: 1.0785x; 1.0538x over previous
//
#include <hip/hip_runtime.h>
#include <math.h>

#define N_NODESC 100000
#define N_EDGESC 1600000
#define NBUCK 1563        // ceil(100000 / 64) -- 64 dst nodes per bucket
#define BSLACK 1280       // slots per bucket region (mean 1024 + 8 sigma)
#define SCHUNK 8192       // edges per scatter block
#define NSBLK 196         // ceil(1.6M / 8192)

// fast tanh: (e^2x - 1) / (e^2x + 1), clamped; ~1e-6 abs error, no libcall
__device__ __forceinline__ float fast_tanh(float x) {
    x = fminf(fmaxf(x, -15.f), 15.f);
    float e = __expf(2.f * x);
    return (e - 1.f) / (e + 1.f);
}

// pack two fp32 into bf16 pair (RNE), lo = a, hi = b
__device__ __forceinline__ unsigned pack_bf16(float a, float b) {
    unsigned ua = __float_as_uint(a), ub = __float_as_uint(b);
    ua += 0x7FFFu + ((ua >> 16) & 1u);
    ub += 0x7FFFu + ((ub >> 16) & 1u);
    return (ua >> 16) | (ub & 0xFFFF0000u);
}
__device__ __forceinline__ float2 unpack_bf16(unsigned p) {
    return make_float2(__uint_as_float(p << 16), __uint_as_float(p & 0xFFFF0000u));
}

__global__ void binit_kernel(int* __restrict__ bcur) {
    int i = blockIdx.x * blockDim.x + threadIdx.x;
    if (i < NBUCK) bcur[i] = i * BSLACK;
}

// ---------------- fused fc1 (tanh) + filt GEMM + channel-0 attention score ----------------
// xs is written as packed bf16 pairs (row = 32 uints = 128 B) to halve the
// gather traffic in agg4. h1 tile goes into LDS for the fused att score.
__global__ __launch_bounds__(256) void gemm_kernel(
    const float* __restrict__ feat,
    const float* __restrict__ w1, const float* __restrict__ b1,
    const float* __restrict__ w2, const float* __restrict__ b2,
    const int* __restrict__ deg_out,
    float* __restrict__ h1, unsigned* __restrict__ xsp,
    const float* __restrict__ aw1, const float* __restrict__ ab1,
    const float* __restrict__ aw2, float* __restrict__ wsum) {
    __shared__ float sf[128 * 68];    // phase 1: feat tile; phase 2: h1 tile
    int tid = threadIdx.x;
    int base = blockIdx.x * 128;
    for (int k = 0; k < 8; k++) {
        int fi = tid + k * 256;
        int node = fi >> 4, f4 = fi & 15;
        float4 v = make_float4(0.f, 0.f, 0.f, 0.f);
        if (base + node < N_NODESC)
            v = ((const float4*)feat)[(size_t)(base + node) * 16 + f4];
        float* d = &sf[node * 68 + f4 * 4];
        d[0] = v.x; d[1] = v.y; d[2] = v.z; d[3] = v.w;
    }
    __syncthreads();

    int lane = tid & 63;
    int og = __builtin_amdgcn_readfirstlane(tid >> 6);
    const float* wp1 = w1 + og * 16 * 64;
    const float* wp2 = w2 + og * 16 * 64;

    float a1[2][16], a2[2][16];
#pragma unroll
    for (int o = 0; o < 16; o++) {
        float bb1 = b1[og * 16 + o], bb2 = b2[og * 16 + o];
        a1[0][o] = bb1; a1[1][o] = bb1;
        a2[0][o] = bb2; a2[1][o] = bb2;
    }

    for (int fq = 0; fq < 16; fq++) {
        float4 fv0 = *(const float4*)&sf[lane * 68 + fq * 4];
        float4 fv1 = *(const float4*)&sf[(lane + 64) * 68 + fq * 4];
#pragma unroll
        for (int o = 0; o < 16; o++) {
            float4 wv1 = *(const float4*)&wp1[o * 64 + fq * 4];
            float4 wv2 = *(const float4*)&wp2[o * 64 + fq * 4];
            a1[0][o] += fv0.x * wv1.x + fv0.y * wv1.y + fv0.z * wv1.z + fv0.w * wv1.w;
            a1[1][o] += fv1.x * wv1.x + fv1.y * wv1.y + fv1.z * wv1.z + fv1.w * wv1.w;
            a2[0][o] += fv0.x * wv2.x + fv0.y * wv2.y + fv0.z * wv2.z + fv0.w * wv2.w;
            a2[1][o] += fv1.x * wv2.x + fv1.y * wv2.y + fv1.z * wv2.z + fv1.w * wv2.w;
        }
    }

    __syncthreads();   // all waves done reading feat tile; sf becomes h1 tile
#pragma unroll
    for (int j = 0; j < 2; j++) {
        int row = lane + j * 64;
        int g = base + row;
        bool ok = g < N_NODESC;
        float is = ok ? rsqrtf(fmaxf((float)deg_out[g], 1.f)) : 0.f;
        unsigned pk[8];
#pragma unroll
        for (int oq = 0; oq < 4; oq++) {
            float4 t;
            t.x = fast_tanh(a1[j][oq * 4 + 0]); t.y = fast_tanh(a1[j][oq * 4 + 1]);
            t.z = fast_tanh(a1[j][oq * 4 + 2]); t.w = fast_tanh(a1[j][oq * 4 + 3]);
            *(float4*)&sf[row * 68 + (og * 4 + oq) * 4] = t;   // h1 tile into LDS
            if (ok) ((float4*)h1)[(size_t)g * 16 + og * 4 + oq] = t;
            pk[oq * 2 + 0] = pack_bf16(a2[j][oq * 4 + 0] * is, a2[j][oq * 4 + 1] * is);
            pk[oq * 2 + 1] = pack_bf16(a2[j][oq * 4 + 2] * is, a2[j][oq * 4 + 3] * is);
        }
        if (ok) {
            ((uint4*)xsp)[(size_t)g * 8 + og * 2 + 0] = make_uint4(pk[0], pk[1], pk[2], pk[3]);
            ((uint4*)xsp)[(size_t)g * 8 + og * 2 + 1] = make_uint4(pk[4], pk[5], pk[6], pk[7]);
        }
    }
    __syncthreads();

    // ---- channel-0 attention score from the LDS h1 tile ----
    int r = tid & 127;
    int kh = __builtin_amdgcn_readfirstlane(tid >> 7);    // wave-uniform k-half
    float acc[16];
#pragma unroll
    for (int k = 0; k < 16; k++) acc[k] = ab1[kh * 16 + k];
    for (int fq = 0; fq < 16; fq++) {
        float4 rv = *(const float4*)&sf[r * 68 + fq * 4];
#pragma unroll
        for (int k = 0; k < 16; k++) {
            int kk = kh * 16 + k;
            acc[k] += rv.x * aw1[(fq * 4 + 0) * 32 + kk]
                    + rv.y * aw1[(fq * 4 + 1) * 32 + kk]
                    + rv.z * aw1[(fq * 4 + 2) * 32 + kk]
                    + rv.w * aw1[(fq * 4 + 3) * 32 + kk];
        }
    }
    float s = 0.f;
#pragma unroll
    for (int k = 0; k < 16; k++) s += fast_tanh(acc[k]) * aw2[kh * 16 + k];
    if (base + r >= N_NODESC) s = 0.f;
#pragma unroll
    for (int off = 32; off; off >>= 1) s += __shfl_down(s, off, 64);
    if ((tid & 63) == 0) atomicAdd(&wsum[0], s);
}

// ---------------- per-block staged counting sort into fixed bucket regions ----------------
__global__ __launch_bounds__(1024) void scatter2_kernel(const int* __restrict__ src,
                                                        const int* __restrict__ dst,
                                                        int* __restrict__ bcur,
                                                        unsigned* __restrict__ bedges,
                                                        int* __restrict__ deg_out) {
    __shared__ int hist[NBUCK];
    int tid = threadIdx.x;
    int e_beg = blockIdx.x * SCHUNK;
    int e_end = min(e_beg + SCHUNK, N_EDGESC);
    for (int i = tid; i < NBUCK; i += 1024) hist[i] = 0;
    __syncthreads();
#pragma unroll 4
    for (int i = e_beg + tid; i < e_end; i += 1024)
        atomicAdd(&hist[dst[i] >> 6], 1);
    __syncthreads();
    for (int i = tid; i < NBUCK; i += 1024) {
        int c = hist[i];
        if (c > 0) hist[i] = atomicAdd(&bcur[i], c);
    }
    __syncthreads();
#pragma unroll 4
    for (int i = e_beg + tid; i < e_end; i += 1024) {
        int s = src[i], d = dst[i];
        int slot = atomicAdd(&hist[d >> 6], 1);
        bedges[slot] = (unsigned)s | ((unsigned)(d & 63) << 17);
        atomicAdd(&deg_out[s], 1);
    }
}

// ---------------- per-bucket aggregation (bf16 xs, 2 edges per load) + channel-1 att ----------------
// Lanes 0..31 process even edges, 32..63 odd edges: one 128B load instruction
// covers 2 edges; the 16-deep batch holds 32 edges in flight per wave.
__global__ __launch_bounds__(256) void agg4_kernel(const int* __restrict__ bcur,
                                                   const unsigned* __restrict__ bedges,
                                                   const unsigned* __restrict__ xsp,
                                                   float* __restrict__ h2,
                                                   const float* __restrict__ aw1,
                                                   const float* __restrict__ ab1,
                                                   const float* __restrict__ aw2,
                                                   float* __restrict__ wsum) {
    __shared__ unsigned eraw[BSLACK];
    __shared__ unsigned eled[BSLACK];
    __shared__ float sh2[64 * 68];     // h2 tile for the attention phase
    __shared__ int loff[65];
    __shared__ int lcnt[64];
    __shared__ int lcur[64];
    int tid = threadIdx.x, lane = tid & 63, wid = tid >> 6;
    int b = blockIdx.x;
    int beg = b * BSLACK;
    int m = bcur[b] - beg;             // edges in this bucket

    if (tid < 64) lcnt[tid] = 0;
    __syncthreads();
    for (int i = tid; i < m; i += 256) {
        unsigned pk = bedges[beg + i];
        eraw[i] = pk;
        atomicAdd(&lcnt[pk >> 17], 1);
    }
    __syncthreads();
    if (wid == 0) {                    // 64-entry exclusive scan in wave 0
        int c = lcnt[lane];
        int v = c;
#pragma unroll
        for (int off = 1; off < 64; off <<= 1) {
            int t = __shfl_up(v, off, 64);
            if (lane >= off) v += t;
        }
        loff[lane] = v - c;
        lcur[lane] = v - c;
        if (lane == 63) loff[64] = v;  // == m
    }
    __syncthreads();
    for (int i = tid; i < m; i += 256) {
        unsigned pk = eraw[i];
        int pos = atomicAdd(&lcur[pk >> 17], 1);
        eled[pos] = pk & 0x1FFFFu;
    }
    __syncthreads();

    int nbase = b * 64;
    int half = lane >> 5;              // 0: even edges, 1: odd edges
    int col = lane & 31;               // uint column within the 32-uint row
#pragma unroll 1
    for (int t = 0; t < 16; t++) {
        int nl = wid * 16 + t;
        int s0 = loff[nl], s1 = loff[nl + 1];
        float accx = 0.f, accy = 0.f;
        for (int k = s0; k < s1; k += 32) {
            int cnt = s1 - k; if (cnt > 32) cnt = 32;   // wave-uniform
            int sv = (int)eled[min(k + col, s1 - 1)];   // lanes 0..31 hold edges k..k+31 (dup high)
            unsigned v[16];
            // unconditional loads (edge index clamped) -> 16 independent 128B
            // loads in flight = 32 edges
#pragma unroll
            for (int j = 0; j < 16; j++) {
                int sj = __shfl(sv, 2 * j + half, 64);
                v[j] = xsp[(size_t)sj * 32 + col];
            }
#pragma unroll
            for (int j = 0; j < 16; j++) {
                float2 f = unpack_bf16(v[j]);
                bool okj = (2 * j + half) < cnt;
                accx += okj ? f.x : 0.f;
                accy += okj ? f.y : 0.f;
            }
        }
        // combine even/odd halves (disjoint edge subsets of the same node)
        accx += __shfl_xor(accx, 32, 64);
        accy += __shfl_xor(accy, 32, 64);
        float isq = rsqrtf(fmaxf((float)(s1 - s0), 1.f));
        accx *= isq; accy *= isq;
        if (half == 0) {
            sh2[nl * 68 + 2 * col]     = accx;
            sh2[nl * 68 + 2 * col + 1] = accy;
            int g = nbase + nl;
            if (g < N_NODESC)
                ((float2*)h2)[(size_t)g * 32 + col] = make_float2(accx, accy);
        }
    }
    __syncthreads();

    // ---- channel-1 attention score from the LDS h2 tile ----
    int r = tid & 63;
    int kq = __builtin_amdgcn_readfirstlane(tid >> 6);    // wave-uniform k-quarter
    float acc2[8];
#pragma unroll
    for (int k = 0; k < 8; k++) acc2[k] = ab1[kq * 8 + k];
    for (int fq = 0; fq < 16; fq++) {
        float4 rv = *(const float4*)&sh2[r * 68 + fq * 4];
#pragma unroll
        for (int k = 0; k < 8; k++) {
            int kk = kq * 8 + k;
            acc2[k] += rv.x * aw1[(fq * 4 + 0) * 32 + kk]
                     + rv.y * aw1[(fq * 4 + 1) * 32 + kk]
                     + rv.z * aw1[(fq * 4 + 2) * 32 + kk]
                     + rv.w * aw1[(fq * 4 + 3) * 32 + kk];
        }
    }
    float s = 0.f;
#pragma unroll
    for (int k = 0; k < 8; k++) s += fast_tanh(acc2[k]) * aw2[kq * 8 + k];
    if (nbase + r >= N_NODESC) s = 0.f;
#pragma unroll
    for (int off = 32; off; off >>= 1) s += __shfl_down(s, off, 64);
    if ((tid & 63) == 0) atomicAdd(&wsum[1], s);
}

__global__ void beta_kernel(const float* __restrict__ wsum, float* __restrict__ beta) {
    float w0 = wsum[0] / (float)N_NODESC, w1 = wsum[1] / (float)N_NODESC;
    float m = fmaxf(w0, w1);
    float e0 = expf(w0 - m), e1 = expf(w1 - m);
    float inv = 1.f / (e0 + e1);
    beta[0] = e0 * inv;
    beta[1] = e1 * inv;
}

// ---------------- fused combine + fc2 ----------------
__global__ __launch_bounds__(256) void out_kernel(const float* __restrict__ h1,
                                                  const float* __restrict__ h2,
                                                  const float* __restrict__ beta,
                                                  const float* __restrict__ w,
                                                  const float* __restrict__ b,
                                                  float* __restrict__ out) {
    __shared__ float sw[16 * 68];
    int tid = threadIdx.x;
    {
        int o = tid >> 4, f4 = tid & 15;
        float4 v = ((const float4*)w)[tid];
        float* d = &sw[o * 68 + f4 * 4];
        d[0] = v.x; d[1] = v.y; d[2] = v.z; d[3] = v.w;
    }
    __syncthreads();
    int o = tid & 15, ln = tid >> 4;
    int node = blockIdx.x * 16 + ln;
    if (node >= N_NODESC) return;
    float b0 = beta[0], b1v = beta[1];
    const float4* r1 = (const float4*)(h1 + (size_t)node * 64);
    const float4* r2 = (const float4*)(h2 + (size_t)node * 64);
    float acc = b[o];
    for (int fq = 0; fq < 16; fq++) {
        float4 x1 = r1[fq], x2 = r2[fq];
        float4 wv = *(const float4*)&sw[o * 68 + fq * 4];
        acc += (b0 * x1.x + b1v * x2.x) * wv.x + (b0 * x1.y + b1v * x2.y) * wv.y
             + (b0 * x1.z + b1v * x2.z) * wv.z + (b0 * x1.w + b1v * x2.w) * wv.w;
    }
    out[(size_t)node * 16 + o] = acc;
}

extern "C" void kernel_launch(void* const* d_in, const int* in_sizes, int n_in,
                              void* d_out, int out_size, void* d_ws, size_t ws_size,
                              hipStream_t stream) {
    (void)in_sizes; (void)n_in; (void)out_size; (void)ws_size;
    const float* feat = (const float*)d_in[0];
    const int*   esrc = (const int*)d_in[1];
    const int*   edst = (const int*)d_in[2];
    const float* fc1w = (const float*)d_in[3];
    const float* fc1b = (const float*)d_in[4];
    const float* fltw = (const float*)d_in[5];
    const float* fltb = (const float*)d_in[6];
    const float* aw1  = (const float*)d_in[7];
    const float* ab1  = (const float*)d_in[8];
    const float* aw2  = (const float*)d_in[9];
    const float* fc2w = (const float*)d_in[10];
    const float* fc2b = (const float*)d_in[11];
    float* out = (float*)d_out;

    char* ws = (char*)d_ws;
    size_t off = 0;
    auto alloc = [&](size_t bytes) {
        char* p = ws + off;
        off += (bytes + 255) & ~(size_t)255;
        return p;
    };
    float*    h1      = (float*)alloc((size_t)N_NODESC * 64 * 4);
    unsigned* xsp     = (unsigned*)alloc((size_t)N_NODESC * 32 * 4);   // bf16-packed xs
    float*    h2      = (float*)alloc((size_t)N_NODESC * 64 * 4);
    int*      deg_out = (int*)alloc((size_t)N_NODESC * 4);
    int*      bcur    = (int*)alloc((size_t)NBUCK * 4);
    unsigned* bedges  = (unsigned*)alloc((size_t)NBUCK * BSLACK * 4);  // 8 MB
    float*    wsum    = (float*)alloc(16 * 4);
    float*    beta    = (float*)alloc(16 * 4);

    hipMemsetAsync(deg_out, 0, (size_t)N_NODESC * 4, stream);
    hipMemsetAsync(wsum, 0, 2 * 4, stream);

    binit_kernel<<<(NBUCK + 255) / 256, 256, 0, stream>>>(bcur);
    scatter2_kernel<<<NSBLK, 1024, 0, stream>>>(esrc, edst, bcur, bedges, deg_out);
    gemm_kernel<<<(N_NODESC + 127) / 128, 256, 0, stream>>>(
        feat, fc1w, fc1b, fltw, fltb, deg_out, h1, xsp, aw1, ab1, aw2, wsum);
    agg4_kernel<<<NBUCK, 256, 0, stream>>>(bcur, bedges, xsp, h2, aw1, ab1, aw2, wsum);
    beta_kernel<<<1, 1, 0, stream>>>(wsum, beta);
    out_kernel<<<(N_NODESC + 15) / 16, 256, 0, stream>>>(h1, h2, beta, fc2w, fc2b, out);
}